// Round 11
// baseline (91.309 us; speedup 1.0000x reference)
//
#include <hip/hip_runtime.h>
#include <math.h>

#define KMAX 8
#define CSTRIDE 64   // ints between expert counters = 256 B -> distinct cache lines

typedef short s16x8 __attribute__((ext_vector_type(8)));
typedef float f32x4 __attribute__((ext_vector_type(4)));

__device__ inline ushort f2bf(float f) {
    union { float f; unsigned u; } v; v.f = f;
    unsigned r = v.u + 0x7fffu + ((v.u >> 16) & 1u);   // RNE
    return (ushort)(r >> 16);
}
__device__ inline float bf2f(ushort b) {
    union { unsigned u; float f; } v; v.u = ((unsigned)b) << 16; return v.f;
}

__device__ inline void gload_lds16(const void* g, void* l) {
    __builtin_amdgcn_global_load_lds(
        (const __attribute__((address_space(1))) unsigned int*)g,
        (__attribute__((address_space(3))) unsigned int*)l, 16, 0, 0);
}

// ---------------------------------------------------------------------------
// K0: per-expert feature norms in double + counts zeroing (replaces the
// hipMemsetAsync graph node).  grid = E blocks of 64 threads.
// ---------------------------------------------------------------------------
__global__ void k_efnorm(const float* __restrict__ ef, int D,
                         double* __restrict__ efn, int* __restrict__ counts) {
    int e = blockIdx.x;
    int lane = threadIdx.x;  // 64
    if (lane == 0) counts[e * CSTRIDE] = 0;
    double s = 0.0;
    for (int i = lane; i < D; i += 64) {
        double v = (double)ef[(size_t)e * D + i];
        s = fma(v, v, s);
    }
    #pragma unroll
    for (int off = 32; off > 0; off >>= 1) s += __shfl_xor(s, off);
    if (lane == 0) efn[e] = sqrt(s);
}

// ---------------------------------------------------------------------------
// K2: W -> bf16, GATED on counts[e] > 0; block (0,0) also computes the
// exclusive prefix scan offs[e] of counts (compact part slots).
// ---------------------------------------------------------------------------
__global__ __launch_bounds__(256) void k_prep_w(
    const float* __restrict__ W, const int* __restrict__ counts,
    int perExpF4, ushort* __restrict__ wbf, int* __restrict__ offs) {
    int e = blockIdx.y;
    if (blockIdx.x == 0 && e == 0 && threadIdx.x == 0) {
        int s = 0;
        for (int e2 = 0; e2 < 32; ++e2) { offs[e2] = s; s += counts[e2 * CSTRIDE]; }
    }
    if (counts[e * CSTRIDE] == 0) return;
    size_t base = (size_t)e * perExpF4;
    #pragma unroll
    for (int j = 0; j < 4; ++j) {
        int idx = (blockIdx.x * 4 + j) * 256 + threadIdx.x;
        if (idx < perExpF4) {
            float4 v = *(const float4*)&W[(base + idx) * 4];
            ushort4 u;
            u.x = f2bf(v.x); u.y = f2bf(v.y); u.z = f2bf(v.z); u.w = f2bf(v.w);
            *(ushort4*)&wbf[(base + idx) * 4] = u;
        }
    }
}

// ---------------------------------------------------------------------------
// K3 v4: scores + top-k + scatter + x->bf16 mirror.  16 tokens/block,
// 256 threads, B/16 = 512 blocks.  CHUNK WIDTH 128 (8 chunks, was 16):
// halves barrier count / per-chunk latency exposure.  T14 async-stage split
// (next chunk to statically-indexed reg arrays before current compute).
// Dots + ||x||^2: f32 chains per 128-chunk, f64 accumulation across chunks
// (error class ~sqrt(2)x the 64-wide version proven rounds 2-10 — still
// ~2e-9 on scores vs the dataset's proven tolerance).  XOR swizzle
// (q ^ (row&15)) stays in [0,32): bank structure identical to 64-wide.
// Hierarchical scatter (round-4 fix) unchanged.
// ---------------------------------------------------------------------------
__global__ __launch_bounds__(256) void k_scores3(
    const float* __restrict__ x, const float* __restrict__ ef,
    const float* __restrict__ trust, const float* __restrict__ stale,
    const double* __restrict__ efn, const int* __restrict__ kp,
    int D, int B, ushort* __restrict__ xbf,
    int* __restrict__ counts, int* __restrict__ lists, int* __restrict__ sel)
{
    __shared__ float xs[16 * 128];          // 8 KB
    __shared__ float efs[32 * 128];         // 16 KB
    __shared__ double sc[16 * 33];
    __shared__ int bcnt[32];
    __shared__ int bbase[32];
    __shared__ unsigned char selb[16 * KMAX];
    __shared__ unsigned char lposb[16 * KMAX];

    int tid = threadIdx.x;
    int tp = tid >> 4, eg = tid & 15;
    int tb = blockIdx.x * 16;

    if (tid < 32) bcnt[tid] = 0;

    int nch = D / 128;                       // 8

    // preload chunk 0 into regs (static indices — rule #20)
    float4 vx[2], ve[4];
    #pragma unroll
    for (int t = 0; t < 2; ++t) {
        int id = t * 256 + tid; int r = id >> 5, q = id & 31;
        vx[t] = *(const float4*)&x[(size_t)(tb + r) * D + q * 4];
    }
    #pragma unroll
    for (int t = 0; t < 4; ++t) {
        int id = t * 256 + tid; int r = id >> 5, q = id & 31;
        ve[t] = *(const float4*)&ef[(size_t)r * D + q * 4];
    }

    double acc0 = 0.0, acc1 = 0.0, axx = 0.0;

    for (int ch = 0; ch < nch; ++ch) {
        // write staged regs -> LDS (swizzled) + xbf mirror
        #pragma unroll
        for (int t = 0; t < 2; ++t) {
            int id = t * 256 + tid; int r = id >> 5, q = id & 31;
            *(float4*)&xs[r * 128 + ((q ^ (r & 15)) << 2)] = vx[t];
            ushort4 u;
            u.x = f2bf(vx[t].x); u.y = f2bf(vx[t].y);
            u.z = f2bf(vx[t].z); u.w = f2bf(vx[t].w);
            *(ushort4*)&xbf[(size_t)(tb + r) * D + ch * 128 + q * 4] = u;
        }
        #pragma unroll
        for (int t = 0; t < 4; ++t) {
            int id = t * 256 + tid; int r = id >> 5, q = id & 31;
            *(float4*)&efs[r * 128 + ((q ^ (r & 15)) << 2)] = ve[t];
        }
        __syncthreads();

        // issue NEXT chunk's loads before compute (T14)
        if (ch + 1 < nch) {
            int k1 = (ch + 1) * 128;
            #pragma unroll
            for (int t = 0; t < 2; ++t) {
                int id = t * 256 + tid; int r = id >> 5, q = id & 31;
                vx[t] = *(const float4*)&x[(size_t)(tb + r) * D + k1 + q * 4];
            }
            #pragma unroll
            for (int t = 0; t < 4; ++t) {
                int id = t * 256 + tid; int r = id >> 5, q = id & 31;
                ve[t] = *(const float4*)&ef[(size_t)r * D + k1 + q * 4];
            }
        }

        float a0 = 0.f, a1 = 0.f, ax = 0.f;
        #pragma unroll
        for (int q = 0; q < 32; ++q) {
            float4 xv = *(const float4*)&xs[tp * 128 + ((q ^ tp) << 2)];
            float4 e0 = *(const float4*)&efs[eg * 128 + ((q ^ eg) << 2)];
            float4 e1 = *(const float4*)&efs[(eg + 16) * 128 + ((q ^ eg) << 2)];
            a0 = fmaf(xv.x, e0.x, a0); a0 = fmaf(xv.y, e0.y, a0);
            a0 = fmaf(xv.z, e0.z, a0); a0 = fmaf(xv.w, e0.w, a0);
            a1 = fmaf(xv.x, e1.x, a1); a1 = fmaf(xv.y, e1.y, a1);
            a1 = fmaf(xv.z, e1.z, a1); a1 = fmaf(xv.w, e1.w, a1);
            ax = fmaf(xv.x, xv.x, ax); ax = fmaf(xv.y, xv.y, ax);
            ax = fmaf(xv.z, xv.z, ax); ax = fmaf(xv.w, xv.w, ax);
        }
        __syncthreads();
        acc0 += (double)a0; acc1 += (double)a1; axx += (double)ax;
    }

    double xn = fmax(sqrt(axx), 1e-8);
    {
        int e0i = eg;
        double en0 = fmax(efn[e0i], 1e-8);
        sc[tp * 33 + e0i] = 0.4 * (double)trust[e0i]
            + 0.2 * (acc0 / (xn * en0) + 1.0)
            + 0.2 * fmax(0.0, 1.0 - (double)stale[e0i]);
        int e1i = eg + 16;
        double en1 = fmax(efn[e1i], 1e-8);
        sc[tp * 33 + e1i] = 0.4 * (double)trust[e1i]
            + 0.2 * (acc1 / (xn * en1) + 1.0)
            + 0.2 * fmax(0.0, 1.0 - (double)stale[e1i]);
    }
    __syncthreads();

    int kk = kp[0]; kk = kk < 1 ? 1 : (kk > KMAX ? KMAX : kk);

    // per-token top-k (strict > scan, lowest-index tie-break == jax.lax.top_k
    // selected set); record selection + LDS-local position
    if (tid < 16) {
        unsigned mask = 0;
        for (int p = 0; p < kk; ++p) {
            double bv = -1e300; int be = 0;
            #pragma unroll
            for (int e = 0; e < 32; ++e) {
                double v = sc[tid * 33 + e];
                if (!((mask >> e) & 1u) && v > bv) { bv = v; be = e; }
            }
            mask |= 1u << be;
            selb[tid * KMAX + p] = (unsigned char)be;
            lposb[tid * KMAX + p] = (unsigned char)atomicAdd(&bcnt[be], 1);
        }
    }
    __syncthreads();
    if (tid < 32) {
        int c = bcnt[tid];
        bbase[tid] = c ? atomicAdd(&counts[tid * CSTRIDE], c) : 0;
    }
    __syncthreads();
    if (tid < 16) {
        int t = tb + tid;
        for (int p = 0; p < kk; ++p) {
            int e = selb[tid * KMAX + p];
            int pos = bbase[e] + lposb[tid * KMAX + p];
            lists[(size_t)e * B + pos] = t;
            sel[(size_t)t * KMAX + p] = (e << 24) | pos;
        }
    }
}

// ---------------------------------------------------------------------------
// K4 v3: grouped expert GEMM (unchanged from round 10 — BM=128, BN=128,
// 512 threads = 8 waves, wave tile 32x64, single-buffer 2-barrier K-loop,
// XOR swizzle both sides, bf16 part stores / atomic fallback).
// ---------------------------------------------------------------------------
__global__ __launch_bounds__(512) void k_moe3(
    const ushort* __restrict__ xbf, const ushort* __restrict__ wbf,
    const float* __restrict__ bias, const int* __restrict__ lists,
    const int* __restrict__ counts, const int* __restrict__ offs,
    const int* __restrict__ kp, int B, int C, int D,
    int usePart, ushort* __restrict__ part, float* __restrict__ out)
{
    int e = blockIdx.z;
    int cnt = counts[e * CSTRIDE];
    int row0 = blockIdx.x * 128;
    if (row0 >= cnt) return;            // uniform: safe before barriers
    int col0 = blockIdx.y * 128;
    int nt = min(128, cnt - row0);

    __shared__ ushort xs[128 * 64];     // 16 KB
    __shared__ ushort wsh[128 * 64];    // 16 KB
    __shared__ int toks[128];

    int tid = threadIdx.x;
    if (tid < 128) toks[tid] = (tid < nt) ? lists[(size_t)e * B + row0 + tid] : 0;
    __syncthreads();

    int lane = tid & 63, wid = tid >> 6;
    int wr = wid >> 1, wc = wid & 1;    // wave tile: rows wr*32, cols wc*64
    int l15 = lane & 15, l16 = lane >> 4;

    f32x4 acc[2][4];
    #pragma unroll
    for (int m = 0; m < 2; ++m)
        #pragma unroll
        for (int n = 0; n < 4; ++n) acc[m][n] = (f32x4){0.f, 0.f, 0.f, 0.f};

    int nch = D / 64;
    for (int ch = 0; ch < nch; ++ch) {
        int k0 = ch * 64;
        #pragma unroll
        for (int t = 0; t < 2; ++t) {
            int id = t * 512 + tid;
            int r = id >> 3, seg = id & 7;
            int ssw = (seg ^ (r & 7)) << 3;
            gload_lds16(&xbf[(size_t)toks[r] * D + k0 + ssw],
                        (char*)xs + (size_t)(t * 512 + wid * 64) * 16);
        }
        #pragma unroll
        for (int t = 0; t < 2; ++t) {
            int id = t * 512 + tid;
            int r = id >> 3, seg = id & 7;
            int ssw = (seg ^ (r & 7)) << 3;
            gload_lds16(&wbf[((size_t)e * C + col0 + r) * D + k0 + ssw],
                        (char*)wsh + (size_t)(t * 512 + wid * 64) * 16);
        }
        __syncthreads();
        #pragma unroll
        for (int ks = 0; ks < 2; ++ks) {
            s16x8 a[2], bfr[4];
            int sbase = ks * 4 + l16;
            #pragma unroll
            for (int m = 0; m < 2; ++m) {
                int r = wr * 32 + m * 16 + l15;
                a[m] = *(const s16x8*)&xs[r * 64 + ((sbase ^ (l15 & 7)) << 3)];
            }
            #pragma unroll
            for (int n = 0; n < 4; ++n) {
                int r = wc * 64 + n * 16 + l15;
                bfr[n] = *(const s16x8*)&wsh[r * 64 + ((sbase ^ (l15 & 7)) << 3)];
            }
            #pragma unroll
            for (int m = 0; m < 2; ++m)
                #pragma unroll
                for (int n = 0; n < 4; ++n)
                    acc[m][n] = __builtin_amdgcn_mfma_f32_16x16x32_bf16(
                        a[m], bfr[n], acc[m][n], 0, 0, 0);
        }
        __syncthreads();
    }

    int kk = kp[0]; kk = kk < 1 ? 1 : (kk > KMAX ? KMAX : kk);
    // C/D layout (m89): col = lane&15, row = (lane>>4)*4 + reg
    if (usePart) {
        int slotBase = offs[e] + row0;
        #pragma unroll
        for (int m = 0; m < 2; ++m) {
            int rbase = wr * 32 + m * 16 + l16 * 4;
            #pragma unroll
            for (int n = 0; n < 4; ++n) {
                int col = col0 + wc * 64 + n * 16 + l15;
                float bv = bias[(size_t)e * C + col];
                #pragma unroll
                for (int r = 0; r < 4; ++r) {
                    int rl = rbase + r;
                    if (rl < nt)
                        part[(size_t)(slotBase + rl) * C + col] =
                            f2bf(acc[m][n][r] + bv);
                }
            }
        }
    } else {
        float invk = 1.0f / (float)kk;
        #pragma unroll
        for (int m = 0; m < 2; ++m) {
            int rbase = wr * 32 + m * 16 + l16 * 4;
            #pragma unroll
            for (int n = 0; n < 4; ++n) {
                int col = col0 + wc * 64 + n * 16 + l15;
                float bv = bias[(size_t)e * C + col];
                #pragma unroll
                for (int r = 0; r < 4; ++r) {
                    int rl = rbase + r;
                    if (rl < nt)
                        atomicAdd(&out[(size_t)toks[rl] * C + col],
                                  invk * (acc[m][n][r] + bv));
                }
            }
        }
    }
}

// ---------------------------------------------------------------------------
// K5: combine — out[t][c] = (1/k) * sum_p bf2f(part[slot_p*C + c]).
// ---------------------------------------------------------------------------
__global__ __launch_bounds__(256) void k_combine(
    const ushort* __restrict__ part, const int* __restrict__ sel,
    const int* __restrict__ offs, const int* __restrict__ kp,
    int C, float* __restrict__ out)
{
    int kk = kp[0]; kk = kk < 1 ? 1 : (kk > KMAX ? KMAX : kk);
    float invk = 1.0f / (float)kk;
    int sub = threadIdx.x >> 6, lane = threadIdx.x & 63;
    int t = blockIdx.x * 4 + sub;
    for (int c = lane * 4; c < C; c += 256) {
        float s0 = 0.f, s1 = 0.f, s2 = 0.f, s3 = 0.f;
        for (int p = 0; p < kk; ++p) {
            int sv = sel[(size_t)t * KMAX + p];
            int slot = offs[sv >> 24] + (sv & 0xFFFFFF);
            ushort4 u = *(const ushort4*)&part[(size_t)slot * C + c];
            s0 += bf2f(u.x); s1 += bf2f(u.y); s2 += bf2f(u.z); s3 += bf2f(u.w);
        }
        float4 o = make_float4(invk * s0, invk * s1, invk * s2, invk * s3);
        *(float4*)&out[(size_t)t * C + c] = o;
    }
}

// ===========================================================================
// Legacy fallback — only if ws_size is too small for the bf16 mirrors.
// ===========================================================================
__global__ __launch_bounds__(256) void k_scores_legacy(
    const float* __restrict__ x, const float* __restrict__ ef,
    const float* __restrict__ trust, const float* __restrict__ stale,
    const double* __restrict__ efn, const int* __restrict__ kp,
    int D, int B, int* __restrict__ counts, int* __restrict__ lists)
{
    __shared__ float xs[32][72];
    __shared__ float efs[32][72];
    __shared__ double sc[32][33];

    int tid = threadIdx.x;
    int tl = tid >> 3, eg = tid & 7;
    int tb = blockIdx.x * 32;

    double acc[4] = {0, 0, 0, 0};
    double axx = 0.0;
    int nch = D / 64;

    for (int ch = 0; ch < nch; ++ch) {
        #pragma unroll
        for (int t = 0; t < 2; ++t) {
            int id = t * 256 + tid;
            int r = id >> 4, q = id & 15;
            float4 v = *(const float4*)&x[(size_t)(tb + r) * D + ch * 64 + q * 4];
            *(float4*)&xs[r][q * 4] = v;
            float4 w = *(const float4*)&ef[(size_t)r * D + ch * 64 + q * 4];
            *(float4*)&efs[r][q * 4] = w;
        }
        __syncthreads();
        #pragma unroll 4
        for (int q = 0; q < 16; ++q) {
            float4 xv = *(const float4*)&xs[tl][q * 4];
            double x0 = xv.x, x1 = xv.y, x2 = xv.z, x3 = xv.w;
            axx = fma(x0, x0, fma(x1, x1, fma(x2, x2, fma(x3, x3, axx))));
            #pragma unroll
            for (int j = 0; j < 4; ++j) {
                float4 ev = *(const float4*)&efs[eg + 8 * j][q * 4];
                acc[j] = fma(x0, (double)ev.x, acc[j]);
                acc[j] = fma(x1, (double)ev.y, acc[j]);
                acc[j] = fma(x2, (double)ev.z, acc[j]);
                acc[j] = fma(x3, (double)ev.w, acc[j]);
            }
        }
        __syncthreads();
    }

    double xn = fmax(sqrt(axx), 1e-8);
    #pragma unroll
    for (int j = 0; j < 4; ++j) {
        int e = eg + 8 * j;
        double en = fmax(efn[e], 1e-8);
        double cosv = acc[j] / (xn * en);
        sc[tl][e] = 0.4 * (double)trust[e] + 0.2 * (cosv + 1.0)
                  + 0.2 * fmax(0.0, 1.0 - (double)stale[e]);
    }
    __syncthreads();

    if (tid < 32) {
        int kk = kp[0]; kk = kk < 1 ? 1 : (kk > KMAX ? KMAX : kk);
        unsigned mask = 0;
        int t = tb + tid;
        for (int p = 0; p < kk; ++p) {
            double bv = -1e300; int be = 0;
            #pragma unroll
            for (int e = 0; e < 32; ++e) {
                double v = sc[tid][e];
                if (!((mask >> e) & 1u) && v > bv) { bv = v; be = e; }
            }
            mask |= 1u << be;
            int pos = atomicAdd(&counts[be * CSTRIDE], 1);
            lists[(size_t)be * B + pos] = t;
        }
    }
}

__global__ __launch_bounds__(512) void k_moe_f32(
    const float* __restrict__ x, const float* __restrict__ W,
    const float* __restrict__ bias, const int* __restrict__ lists,
    const int* __restrict__ counts, const int* __restrict__ kp,
    int B, int C, int D, float* __restrict__ out)
{
    int e = blockIdx.z;
    int cnt = counts[e * CSTRIDE];
    int row0 = blockIdx.x * 128;
    if (row0 >= cnt) return;
    int col0 = blockIdx.y * 256;
    int nt = min(128, cnt - row0);

    __shared__ ushort xs[128 * 72];
    __shared__ ushort wsh[256 * 72];
    __shared__ int toks[128];

    int tid = threadIdx.x;
    if (tid < 128) toks[tid] = (tid < nt) ? lists[(size_t)e * B + row0 + tid] : 0;
    __syncthreads();

    int lane = tid & 63, wid = tid >> 6;
    int wr = wid >> 2, wc = wid & 3;
    int l15 = lane & 15, l16 = lane >> 4;

    f32x4 acc[4][4];
    #pragma unroll
    for (int m = 0; m < 4; ++m)
        #pragma unroll
        for (int n = 0; n < 4; ++n) acc[m][n] = (f32x4){0.f, 0.f, 0.f, 0.f};

    int nch = D / 64;
    for (int ch = 0; ch < nch; ++ch) {
        int k0 = ch * 64;
        #pragma unroll
        for (int t = 0; t < 4; ++t) {
            int id = t * 512 + tid;
            int r = id >> 4, q = id & 15;
            float4 v = (r < nt)
                ? *(const float4*)&x[(size_t)toks[r] * D + k0 + q * 4]
                : make_float4(0.f, 0.f, 0.f, 0.f);
            ushort4 u;
            u.x = f2bf(v.x); u.y = f2bf(v.y); u.z = f2bf(v.z); u.w = f2bf(v.w);
            *(ushort4*)&xs[r * 72 + q * 4] = u;
        }
        #pragma unroll
        for (int t = 0; t < 8; ++t) {
            int id = t * 512 + tid;
            int r = id >> 4, q = id & 15;
            float4 v = *(const float4*)&W[((size_t)e * C + col0 + r) * D + k0 + q * 4];
            ushort4 u;
            u.x = f2bf(v.x); u.y = f2bf(v.y); u.z = f2bf(v.z); u.w = f2bf(v.w);
            *(ushort4*)&wsh[r * 72 + q * 4] = u;
        }
        __syncthreads();
        #pragma unroll
        for (int ks = 0; ks < 2; ++ks) {
            s16x8 a[4], bfr[4];
            #pragma unroll
            for (int m = 0; m < 4; ++m)
                a[m] = *(const s16x8*)&xs[(wr * 64 + m * 16 + l15) * 72 + ks * 32 + l16 * 8];
            #pragma unroll
            for (int n = 0; n < 4; ++n)
                bfr[n] = *(const s16x8*)&wsh[(wc * 64 + n * 16 + l15) * 72 + ks * 32 + l16 * 8];
            #pragma unroll
            for (int m = 0; m < 4; ++m)
                #pragma unroll
                for (int n = 0; n < 4; ++n)
                    acc[m][n] = __builtin_amdgcn_mfma_f32_16x16x32_bf16(
                        a[m], bfr[n], acc[m][n], 0, 0, 0);
        }
        __syncthreads();
    }

    int kk = kp[0]; kk = kk < 1 ? 1 : (kk > KMAX ? KMAX : kk);
    float invk = 1.0f / (float)kk;
    #pragma unroll
    for (int m = 0; m < 4; ++m) {
        int rbase = wr * 64 + m * 16 + l16 * 4;
        #pragma unroll
        for (int n = 0; n < 4; ++n) {
            int col = col0 + wc * 64 + n * 16 + l15;
            float bv = bias[(size_t)e * C + col];
            #pragma unroll
            for (int r = 0; r < 4; ++r) {
                int rl = rbase + r;
                if (rl < nt)
                    atomicAdd(&out[(size_t)toks[rl] * C + col],
                              invk * (acc[m][n][r] + bv));
            }
        }
    }
}

// ---------------------------------------------------------------------------
extern "C" void kernel_launch(void* const* d_in, const int* in_sizes, int n_in,
                              void* d_out, int out_size, void* d_ws, size_t ws_size,
                              hipStream_t stream) {
    const float* x     = (const float*)d_in[0];
    const float* ef    = (const float*)d_in[1];
    const float* trust = (const float*)d_in[2];
    const float* stale = (const float*)d_in[3];
    const float* W     = (const float*)d_in[4];
    const float* b     = (const float*)d_in[5];
    const int*   kp    = (const int*)d_in[6];

    int E = in_sizes[2];            // 32
    int D = in_sizes[1] / E;        // 1024
    int B = in_sizes[0] / D;        // 8192
    int C = in_sizes[5] / E;        // 256
    float* out = (float*)d_out;

    // workspace layout
    char* ws = (char*)d_ws;
    double* efn   = (double*)ws;                       // 256 B
    int*    counts= (int*)(ws + 256);                  // 32*CSTRIDE*4 = 8 KB
    size_t off_offs = 256 + 32 * CSTRIDE * 4;
    int*    offs  = (int*)(ws + off_offs);             // 256 B
    size_t off_sel = off_offs + 256;
    int*    sel   = (int*)(ws + off_sel);              // B*KMAX*4
    size_t off_lists = off_sel + (size_t)B * KMAX * 4;
    int*    lists = (int*)(ws + off_lists);            // E*B*4
    size_t off_xbf = off_lists + (size_t)E * B * 4;
    off_xbf = (off_xbf + 255) & ~(size_t)255;
    ushort* xbf = (ushort*)(ws + off_xbf);             // B*D*2
    size_t off_wbf = off_xbf + (size_t)B * D * 2;
    ushort* wbf = (ushort*)(ws + off_wbf);             // E*C*D*2
    size_t off_part = off_wbf + (size_t)E * C * D * 2;
    off_part = (off_part + 255) & ~(size_t)255;
    ushort* part = (ushort*)(ws + off_part);           // B*KMAX*C*2 bf16 slots
    size_t need_mid  = off_part;
    size_t need_full = off_part + (size_t)B * KMAX * C * 2;

    bool fullPath = ws_size >= need_mid;
    int usePart = (fullPath && ws_size >= need_full) ? 1 : 0;

    if (!usePart)
        hipMemsetAsync(d_out, 0, (size_t)out_size * sizeof(float), stream);

    k_efnorm<<<E, 64, 0, stream>>>(ef, D, efn, counts);  // also zeroes counts

    if (fullPath) {
        k_scores3<<<B / 16, 256, 0, stream>>>(x, ef, trust, stale, efn,
                                              kp, D, B, xbf, counts, lists, sel);
        int perExpF4 = (C * D) / 4;
        dim3 wgrid((perExpF4 + 1023) / 1024, E);
        k_prep_w<<<wgrid, 256, 0, stream>>>(W, counts, perExpF4, wbf, offs);
        dim3 grid((B + 127) / 128, C / 128, E);
        k_moe3<<<grid, 512, 0, stream>>>(xbf, wbf, b, lists, counts, offs, kp,
                                         B, C, D, usePart, part, out);
        if (usePart)
            k_combine<<<B / 4, 256, 0, stream>>>(part, sel, offs, kp, C, out);
    } else {
        k_scores_legacy<<<B / 32, 256, 0, stream>>>(x, ef, trust, stale, efn,
                                                    kp, D, B, counts, lists);
        dim3 grid((B + 127) / 128, C / 256, E);
        k_moe_f32<<<grid, 512, 0, stream>>>(x, W, b, lists, counts, kp,
                                            B, C, D, out);
    }
}

// Round 12
// 83.613 us; speedup vs baseline: 1.0920x; 1.0920x over previous
//
#include <hip/hip_runtime.h>
#include <math.h>

#define KMAX 8
#define CSTRIDE 64   // ints between expert counters = 256 B -> distinct cache lines

typedef short s16x8 __attribute__((ext_vector_type(8)));
typedef float f32x4 __attribute__((ext_vector_type(4)));

__device__ inline ushort f2bf(float f) {
    union { float f; unsigned u; } v; v.f = f;
    unsigned r = v.u + 0x7fffu + ((v.u >> 16) & 1u);   // RNE
    return (ushort)(r >> 16);
}
__device__ inline float bf2f(ushort b) {
    union { unsigned u; float f; } v; v.u = ((unsigned)b) << 16; return v.f;
}

__device__ inline void gload_lds16(const void* g, void* l) {
    __builtin_amdgcn_global_load_lds(
        (const __attribute__((address_space(1))) unsigned int*)g,
        (__attribute__((address_space(3))) unsigned int*)l, 16, 0, 0);
}

// ---------------------------------------------------------------------------
// K0: per-expert feature norms in double + counts zeroing (replaces the
// hipMemsetAsync graph node).  grid = E blocks of 64 threads.
// ---------------------------------------------------------------------------
__global__ void k_efnorm(const float* __restrict__ ef, int D,
                         double* __restrict__ efn, int* __restrict__ counts) {
    int e = blockIdx.x;
    int lane = threadIdx.x;  // 64
    if (lane == 0) counts[e * CSTRIDE] = 0;
    double s = 0.0;
    for (int i = lane; i < D; i += 64) {
        double v = (double)ef[(size_t)e * D + i];
        s = fma(v, v, s);
    }
    #pragma unroll
    for (int off = 32; off > 0; off >>= 1) s += __shfl_xor(s, off);
    if (lane == 0) efn[e] = sqrt(s);
}

// ---------------------------------------------------------------------------
// K2: W -> bf16, GATED on counts[e] > 0; block (0,0) also computes the
// exclusive prefix scan offs[e] of counts (compact part slots).
// ---------------------------------------------------------------------------
__global__ __launch_bounds__(256) void k_prep_w(
    const float* __restrict__ W, const int* __restrict__ counts,
    int perExpF4, ushort* __restrict__ wbf, int* __restrict__ offs) {
    int e = blockIdx.y;
    if (blockIdx.x == 0 && e == 0 && threadIdx.x == 0) {
        int s = 0;
        for (int e2 = 0; e2 < 32; ++e2) { offs[e2] = s; s += counts[e2 * CSTRIDE]; }
    }
    if (counts[e * CSTRIDE] == 0) return;
    size_t base = (size_t)e * perExpF4;
    #pragma unroll
    for (int j = 0; j < 4; ++j) {
        int idx = (blockIdx.x * 4 + j) * 256 + threadIdx.x;
        if (idx < perExpF4) {
            float4 v = *(const float4*)&W[(base + idx) * 4];
            ushort4 u;
            u.x = f2bf(v.x); u.y = f2bf(v.y); u.z = f2bf(v.z); u.w = f2bf(v.w);
            *(ushort4*)&wbf[(base + idx) * 4] = u;
        }
    }
}

// ---------------------------------------------------------------------------
// K3 (round-10 proven version, chunk width 64 — the chunk-128 rewrite of
// round 11 regressed ~2x and is reverted): scores + top-k + scatter +
// x->bf16 mirror + sel[] slot map.  16 tokens/block, 256 threads, B/16 = 512
// blocks.  T14 async-stage split (next chunk to regs before current
// compute).  Dots + ||x||^2: f32 chains per 64-chunk, f64 accumulation
// across chunks (tolerance proven rounds 1-10).  Hierarchical scatter
// (round-4 fix: LDS counters then one global atomicAdd per (block, expert)
// on 256B-spaced lines).
// ---------------------------------------------------------------------------
__global__ __launch_bounds__(256) void k_scores3(
    const float* __restrict__ x, const float* __restrict__ ef,
    const float* __restrict__ trust, const float* __restrict__ stale,
    const double* __restrict__ efn, const int* __restrict__ kp,
    int D, int B, ushort* __restrict__ xbf,
    int* __restrict__ counts, int* __restrict__ lists, int* __restrict__ sel)
{
    __shared__ float xs[16 * 64];           // 4 KB
    __shared__ float efs[32 * 64];          // 8 KB
    __shared__ double sc[16 * 33];
    __shared__ int bcnt[32];
    __shared__ int bbase[32];
    __shared__ unsigned char selb[16 * KMAX];
    __shared__ unsigned char lposb[16 * KMAX];

    int tid = threadIdx.x;
    int tp = tid >> 4, eg = tid & 15;
    int tb = blockIdx.x * 16;

    if (tid < 32) bcnt[tid] = 0;

    int rx = tid >> 4, qx = tid & 15;
    int re0 = tid >> 4, re1 = 16 + (tid >> 4);
    int qe = tid & 15;

    int nch = D / 64;

    float4 vx  = *(const float4*)&x[(size_t)(tb + rx) * D + qx * 4];
    float4 ve0 = *(const float4*)&ef[(size_t)re0 * D + qe * 4];
    float4 ve1 = *(const float4*)&ef[(size_t)re1 * D + qe * 4];

    double acc0 = 0.0, acc1 = 0.0, axx = 0.0;

    for (int ch = 0; ch < nch; ++ch) {
        *(float4*)&xs[rx * 64 + ((qx ^ rx) << 2)] = vx;
        {
            ushort4 u;
            u.x = f2bf(vx.x); u.y = f2bf(vx.y); u.z = f2bf(vx.z); u.w = f2bf(vx.w);
            *(ushort4*)&xbf[(size_t)(tb + rx) * D + ch * 64 + qx * 4] = u;
        }
        *(float4*)&efs[re0 * 64 + ((qe ^ (re0 & 15)) << 2)] = ve0;
        *(float4*)&efs[re1 * 64 + ((qe ^ (re1 & 15)) << 2)] = ve1;
        __syncthreads();

        if (ch + 1 < nch) {
            int k1 = (ch + 1) * 64;
            vx  = *(const float4*)&x[(size_t)(tb + rx) * D + k1 + qx * 4];
            ve0 = *(const float4*)&ef[(size_t)re0 * D + k1 + qe * 4];
            ve1 = *(const float4*)&ef[(size_t)re1 * D + k1 + qe * 4];
        }

        float a0 = 0.f, a1 = 0.f, ax = 0.f;
        #pragma unroll
        for (int q = 0; q < 16; ++q) {
            float4 xv = *(const float4*)&xs[tp * 64 + ((q ^ tp) << 2)];
            float4 e0 = *(const float4*)&efs[eg * 64 + ((q ^ eg) << 2)];
            float4 e1 = *(const float4*)&efs[(eg + 16) * 64 + ((q ^ eg) << 2)];
            a0 = fmaf(xv.x, e0.x, a0); a0 = fmaf(xv.y, e0.y, a0);
            a0 = fmaf(xv.z, e0.z, a0); a0 = fmaf(xv.w, e0.w, a0);
            a1 = fmaf(xv.x, e1.x, a1); a1 = fmaf(xv.y, e1.y, a1);
            a1 = fmaf(xv.z, e1.z, a1); a1 = fmaf(xv.w, e1.w, a1);
            ax = fmaf(xv.x, xv.x, ax); ax = fmaf(xv.y, xv.y, ax);
            ax = fmaf(xv.z, xv.z, ax); ax = fmaf(xv.w, xv.w, ax);
        }
        __syncthreads();
        acc0 += (double)a0; acc1 += (double)a1; axx += (double)ax;
    }

    double xn = fmax(sqrt(axx), 1e-8);
    {
        int e0i = eg;
        double en0 = fmax(efn[e0i], 1e-8);
        sc[tp * 33 + e0i] = 0.4 * (double)trust[e0i]
            + 0.2 * (acc0 / (xn * en0) + 1.0)
            + 0.2 * fmax(0.0, 1.0 - (double)stale[e0i]);
        int e1i = eg + 16;
        double en1 = fmax(efn[e1i], 1e-8);
        sc[tp * 33 + e1i] = 0.4 * (double)trust[e1i]
            + 0.2 * (acc1 / (xn * en1) + 1.0)
            + 0.2 * fmax(0.0, 1.0 - (double)stale[e1i]);
    }
    __syncthreads();

    int kk = kp[0]; kk = kk < 1 ? 1 : (kk > KMAX ? KMAX : kk);

    // per-token top-k (strict > scan, lowest-index tie-break == jax.lax.top_k
    // selected set); record selection + LDS-local position
    if (tid < 16) {
        unsigned mask = 0;
        for (int p = 0; p < kk; ++p) {
            double bv = -1e300; int be = 0;
            #pragma unroll
            for (int e = 0; e < 32; ++e) {
                double v = sc[tid * 33 + e];
                if (!((mask >> e) & 1u) && v > bv) { bv = v; be = e; }
            }
            mask |= 1u << be;
            selb[tid * KMAX + p] = (unsigned char)be;
            lposb[tid * KMAX + p] = (unsigned char)atomicAdd(&bcnt[be], 1);
        }
    }
    __syncthreads();
    if (tid < 32) {
        int c = bcnt[tid];
        bbase[tid] = c ? atomicAdd(&counts[tid * CSTRIDE], c) : 0;
    }
    __syncthreads();
    if (tid < 16) {
        int t = tb + tid;
        for (int p = 0; p < kk; ++p) {
            int e = selb[tid * KMAX + p];
            int pos = bbase[e] + lposb[tid * KMAX + p];
            lists[(size_t)e * B + pos] = t;
            sel[(size_t)t * KMAX + p] = (e << 24) | pos;
        }
    }
}

// ---------------------------------------------------------------------------
// K4 v3: grouped expert GEMM (round-10 proven — BM=128, BN=128, 512 threads
// = 8 waves, wave tile 32x64, single-buffer 2-barrier K-loop, XOR swizzle
// both sides -> 0 conflicts, bf16 part stores / atomic fallback).
// ---------------------------------------------------------------------------
__global__ __launch_bounds__(512) void k_moe3(
    const ushort* __restrict__ xbf, const ushort* __restrict__ wbf,
    const float* __restrict__ bias, const int* __restrict__ lists,
    const int* __restrict__ counts, const int* __restrict__ offs,
    const int* __restrict__ kp, int B, int C, int D,
    int usePart, ushort* __restrict__ part, float* __restrict__ out)
{
    int e = blockIdx.z;
    int cnt = counts[e * CSTRIDE];
    int row0 = blockIdx.x * 128;
    if (row0 >= cnt) return;            // uniform: safe before barriers
    int col0 = blockIdx.y * 128;
    int nt = min(128, cnt - row0);

    __shared__ ushort xs[128 * 64];     // 16 KB
    __shared__ ushort wsh[128 * 64];    // 16 KB
    __shared__ int toks[128];

    int tid = threadIdx.x;
    if (tid < 128) toks[tid] = (tid < nt) ? lists[(size_t)e * B + row0 + tid] : 0;
    __syncthreads();

    int lane = tid & 63, wid = tid >> 6;
    int wr = wid >> 1, wc = wid & 1;    // wave tile: rows wr*32, cols wc*64
    int l15 = lane & 15, l16 = lane >> 4;

    f32x4 acc[2][4];
    #pragma unroll
    for (int m = 0; m < 2; ++m)
        #pragma unroll
        for (int n = 0; n < 4; ++n) acc[m][n] = (f32x4){0.f, 0.f, 0.f, 0.f};

    int nch = D / 64;
    for (int ch = 0; ch < nch; ++ch) {
        int k0 = ch * 64;
        #pragma unroll
        for (int t = 0; t < 2; ++t) {
            int id = t * 512 + tid;
            int r = id >> 3, seg = id & 7;
            int ssw = (seg ^ (r & 7)) << 3;
            gload_lds16(&xbf[(size_t)toks[r] * D + k0 + ssw],
                        (char*)xs + (size_t)(t * 512 + wid * 64) * 16);
        }
        #pragma unroll
        for (int t = 0; t < 2; ++t) {
            int id = t * 512 + tid;
            int r = id >> 3, seg = id & 7;
            int ssw = (seg ^ (r & 7)) << 3;
            gload_lds16(&wbf[((size_t)e * C + col0 + r) * D + k0 + ssw],
                        (char*)wsh + (size_t)(t * 512 + wid * 64) * 16);
        }
        __syncthreads();
        #pragma unroll
        for (int ks = 0; ks < 2; ++ks) {
            s16x8 a[2], bfr[4];
            int sbase = ks * 4 + l16;
            #pragma unroll
            for (int m = 0; m < 2; ++m) {
                int r = wr * 32 + m * 16 + l15;
                a[m] = *(const s16x8*)&xs[r * 64 + ((sbase ^ (l15 & 7)) << 3)];
            }
            #pragma unroll
            for (int n = 0; n < 4; ++n) {
                int r = wc * 64 + n * 16 + l15;
                bfr[n] = *(const s16x8*)&wsh[r * 64 + ((sbase ^ (l15 & 7)) << 3)];
            }
            #pragma unroll
            for (int m = 0; m < 2; ++m)
                #pragma unroll
                for (int n = 0; n < 4; ++n)
                    acc[m][n] = __builtin_amdgcn_mfma_f32_16x16x32_bf16(
                        a[m], bfr[n], acc[m][n], 0, 0, 0);
        }
        __syncthreads();
    }

    int kk = kp[0]; kk = kk < 1 ? 1 : (kk > KMAX ? KMAX : kk);
    // C/D layout (m89): col = lane&15, row = (lane>>4)*4 + reg
    if (usePart) {
        int slotBase = offs[e] + row0;
        #pragma unroll
        for (int m = 0; m < 2; ++m) {
            int rbase = wr * 32 + m * 16 + l16 * 4;
            #pragma unroll
            for (int n = 0; n < 4; ++n) {
                int col = col0 + wc * 64 + n * 16 + l15;
                float bv = bias[(size_t)e * C + col];
                #pragma unroll
                for (int r = 0; r < 4; ++r) {
                    int rl = rbase + r;
                    if (rl < nt)
                        part[(size_t)(slotBase + rl) * C + col] =
                            f2bf(acc[m][n][r] + bv);
                }
            }
        }
    } else {
        float invk = 1.0f / (float)kk;
        #pragma unroll
        for (int m = 0; m < 2; ++m) {
            int rbase = wr * 32 + m * 16 + l16 * 4;
            #pragma unroll
            for (int n = 0; n < 4; ++n) {
                int col = col0 + wc * 64 + n * 16 + l15;
                float bv = bias[(size_t)e * C + col];
                #pragma unroll
                for (int r = 0; r < 4; ++r) {
                    int rl = rbase + r;
                    if (rl < nt)
                        atomicAdd(&out[(size_t)toks[rl] * C + col],
                                  invk * (acc[m][n][r] + bv));
                }
            }
        }
    }
}

// ---------------------------------------------------------------------------
// K5: combine — out[t][c] = (1/k) * sum_p bf2f(part[slot_p*C + c]).
// ---------------------------------------------------------------------------
__global__ __launch_bounds__(256) void k_combine(
    const ushort* __restrict__ part, const int* __restrict__ sel,
    const int* __restrict__ offs, const int* __restrict__ kp,
    int C, float* __restrict__ out)
{
    int kk = kp[0]; kk = kk < 1 ? 1 : (kk > KMAX ? KMAX : kk);
    float invk = 1.0f / (float)kk;
    int sub = threadIdx.x >> 6, lane = threadIdx.x & 63;
    int t = blockIdx.x * 4 + sub;
    for (int c = lane * 4; c < C; c += 256) {
        float s0 = 0.f, s1 = 0.f, s2 = 0.f, s3 = 0.f;
        for (int p = 0; p < kk; ++p) {
            int sv = sel[(size_t)t * KMAX + p];
            int slot = offs[sv >> 24] + (sv & 0xFFFFFF);
            ushort4 u = *(const ushort4*)&part[(size_t)slot * C + c];
            s0 += bf2f(u.x); s1 += bf2f(u.y); s2 += bf2f(u.z); s3 += bf2f(u.w);
        }
        float4 o = make_float4(invk * s0, invk * s1, invk * s2, invk * s3);
        *(float4*)&out[(size_t)t * C + c] = o;
    }
}

// ===========================================================================
// Legacy fallback — only if ws_size is too small for the bf16 mirrors.
// ===========================================================================
__global__ __launch_bounds__(256) void k_scores_legacy(
    const float* __restrict__ x, const float* __restrict__ ef,
    const float* __restrict__ trust, const float* __restrict__ stale,
    const double* __restrict__ efn, const int* __restrict__ kp,
    int D, int B, int* __restrict__ counts, int* __restrict__ lists)
{
    __shared__ float xs[32][72];
    __shared__ float efs[32][72];
    __shared__ double sc[32][33];

    int tid = threadIdx.x;
    int tl = tid >> 3, eg = tid & 7;
    int tb = blockIdx.x * 32;

    double acc[4] = {0, 0, 0, 0};
    double axx = 0.0;
    int nch = D / 64;

    for (int ch = 0; ch < nch; ++ch) {
        #pragma unroll
        for (int t = 0; t < 2; ++t) {
            int id = t * 256 + tid;
            int r = id >> 4, q = id & 15;
            float4 v = *(const float4*)&x[(size_t)(tb + r) * D + ch * 64 + q * 4];
            *(float4*)&xs[r][q * 4] = v;
            float4 w = *(const float4*)&ef[(size_t)r * D + ch * 64 + q * 4];
            *(float4*)&efs[r][q * 4] = w;
        }
        __syncthreads();
        #pragma unroll 4
        for (int q = 0; q < 16; ++q) {
            float4 xv = *(const float4*)&xs[tl][q * 4];
            double x0 = xv.x, x1 = xv.y, x2 = xv.z, x3 = xv.w;
            axx = fma(x0, x0, fma(x1, x1, fma(x2, x2, fma(x3, x3, axx))));
            #pragma unroll
            for (int j = 0; j < 4; ++j) {
                float4 ev = *(const float4*)&efs[eg + 8 * j][q * 4];
                acc[j] = fma(x0, (double)ev.x, acc[j]);
                acc[j] = fma(x1, (double)ev.y, acc[j]);
                acc[j] = fma(x2, (double)ev.z, acc[j]);
                acc[j] = fma(x3, (double)ev.w, acc[j]);
            }
        }
        __syncthreads();
    }

    double xn = fmax(sqrt(axx), 1e-8);
    #pragma unroll
    for (int j = 0; j < 4; ++j) {
        int e = eg + 8 * j;
        double en = fmax(efn[e], 1e-8);
        double cosv = acc[j] / (xn * en);
        sc[tl][e] = 0.4 * (double)trust[e] + 0.2 * (cosv + 1.0)
                  + 0.2 * fmax(0.0, 1.0 - (double)stale[e]);
    }
    __syncthreads();

    if (tid < 32) {
        int kk = kp[0]; kk = kk < 1 ? 1 : (kk > KMAX ? KMAX : kk);
        unsigned mask = 0;
        int t = tb + tid;
        for (int p = 0; p < kk; ++p) {
            double bv = -1e300; int be = 0;
            #pragma unroll
            for (int e = 0; e < 32; ++e) {
                double v = sc[tid][e];
                if (!((mask >> e) & 1u) && v > bv) { bv = v; be = e; }
            }
            mask |= 1u << be;
            int pos = atomicAdd(&counts[be * CSTRIDE], 1);
            lists[(size_t)be * B + pos] = t;
        }
    }
}

__global__ __launch_bounds__(512) void k_moe_f32(
    const float* __restrict__ x, const float* __restrict__ W,
    const float* __restrict__ bias, const int* __restrict__ lists,
    const int* __restrict__ counts, const int* __restrict__ kp,
    int B, int C, int D, float* __restrict__ out)
{
    int e = blockIdx.z;
    int cnt = counts[e * CSTRIDE];
    int row0 = blockIdx.x * 128;
    if (row0 >= cnt) return;
    int col0 = blockIdx.y * 256;
    int nt = min(128, cnt - row0);

    __shared__ ushort xs[128 * 72];
    __shared__ ushort wsh[256 * 72];
    __shared__ int toks[128];

    int tid = threadIdx.x;
    if (tid < 128) toks[tid] = (tid < nt) ? lists[(size_t)e * B + row0 + tid] : 0;
    __syncthreads();

    int lane = tid & 63, wid = tid >> 6;
    int wr = wid >> 2, wc = wid & 3;
    int l15 = lane & 15, l16 = lane >> 4;

    f32x4 acc[4][4];
    #pragma unroll
    for (int m = 0; m < 4; ++m)
        #pragma unroll
        for (int n = 0; n < 4; ++n) acc[m][n] = (f32x4){0.f, 0.f, 0.f, 0.f};

    int nch = D / 64;
    for (int ch = 0; ch < nch; ++ch) {
        int k0 = ch * 64;
        #pragma unroll
        for (int t = 0; t < 4; ++t) {
            int id = t * 512 + tid;
            int r = id >> 4, q = id & 15;
            float4 v = (r < nt)
                ? *(const float4*)&x[(size_t)toks[r] * D + k0 + q * 4]
                : make_float4(0.f, 0.f, 0.f, 0.f);
            ushort4 u;
            u.x = f2bf(v.x); u.y = f2bf(v.y); u.z = f2bf(v.z); u.w = f2bf(v.w);
            *(ushort4*)&xs[r * 72 + q * 4] = u;
        }
        #pragma unroll
        for (int t = 0; t < 8; ++t) {
            int id = t * 512 + tid;
            int r = id >> 4, q = id & 15;
            float4 v = *(const float4*)&W[((size_t)e * C + col0 + r) * D + k0 + q * 4];
            ushort4 u;
            u.x = f2bf(v.x); u.y = f2bf(v.y); u.z = f2bf(v.z); u.w = f2bf(v.w);
            *(ushort4*)&wsh[r * 72 + q * 4] = u;
        }
        __syncthreads();
        #pragma unroll
        for (int ks = 0; ks < 2; ++ks) {
            s16x8 a[4], bfr[4];
            #pragma unroll
            for (int m = 0; m < 4; ++m)
                a[m] = *(const s16x8*)&xs[(wr * 64 + m * 16 + l15) * 72 + ks * 32 + l16 * 8];
            #pragma unroll
            for (int n = 0; n < 4; ++n)
                bfr[n] = *(const s16x8*)&wsh[(wc * 64 + n * 16 + l15) * 72 + ks * 32 + l16 * 8];
            #pragma unroll
            for (int m = 0; m < 4; ++m)
                #pragma unroll
                for (int n = 0; n < 4; ++n)
                    acc[m][n] = __builtin_amdgcn_mfma_f32_16x16x32_bf16(
                        a[m], bfr[n], acc[m][n], 0, 0, 0);
        }
        __syncthreads();
    }

    int kk = kp[0]; kk = kk < 1 ? 1 : (kk > KMAX ? KMAX : kk);
    float invk = 1.0f / (float)kk;
    #pragma unroll
    for (int m = 0; m < 4; ++m) {
        int rbase = wr * 64 + m * 16 + l16 * 4;
        #pragma unroll
        for (int n = 0; n < 4; ++n) {
            int col = col0 + wc * 64 + n * 16 + l15;
            float bv = bias[(size_t)e * C + col];
            #pragma unroll
            for (int r = 0; r < 4; ++r) {
                int rl = rbase + r;
                if (rl < nt)
                    atomicAdd(&out[(size_t)toks[rl] * C + col],
                              invk * (acc[m][n][r] + bv));
            }
        }
    }
}

// ---------------------------------------------------------------------------
extern "C" void kernel_launch(void* const* d_in, const int* in_sizes, int n_in,
                              void* d_out, int out_size, void* d_ws, size_t ws_size,
                              hipStream_t stream) {
    const float* x     = (const float*)d_in[0];
    const float* ef    = (const float*)d_in[1];
    const float* trust = (const float*)d_in[2];
    const float* stale = (const float*)d_in[3];
    const float* W     = (const float*)d_in[4];
    const float* b     = (const float*)d_in[5];
    const int*   kp    = (const int*)d_in[6];

    int E = in_sizes[2];            // 32
    int D = in_sizes[1] / E;        // 1024
    int B = in_sizes[0] / D;        // 8192
    int C = in_sizes[5] / E;        // 256
    float* out = (float*)d_out;

    // workspace layout
    char* ws = (char*)d_ws;
    double* efn   = (double*)ws;                       // 256 B
    int*    counts= (int*)(ws + 256);                  // 32*CSTRIDE*4 = 8 KB
    size_t off_offs = 256 + 32 * CSTRIDE * 4;
    int*    offs  = (int*)(ws + off_offs);             // 256 B
    size_t off_sel = off_offs + 256;
    int*    sel   = (int*)(ws + off_sel);              // B*KMAX*4
    size_t off_lists = off_sel + (size_t)B * KMAX * 4;
    int*    lists = (int*)(ws + off_lists);            // E*B*4
    size_t off_xbf = off_lists + (size_t)E * B * 4;
    off_xbf = (off_xbf + 255) & ~(size_t)255;
    ushort* xbf = (ushort*)(ws + off_xbf);             // B*D*2
    size_t off_wbf = off_xbf + (size_t)B * D * 2;
    ushort* wbf = (ushort*)(ws + off_wbf);             // E*C*D*2
    size_t off_part = off_wbf + (size_t)E * C * D * 2;
    off_part = (off_part + 255) & ~(size_t)255;
    ushort* part = (ushort*)(ws + off_part);           // B*KMAX*C*2 bf16 slots
    size_t need_mid  = off_part;
    size_t need_full = off_part + (size_t)B * KMAX * C * 2;

    bool fullPath = ws_size >= need_mid;
    int usePart = (fullPath && ws_size >= need_full) ? 1 : 0;

    if (!usePart)
        hipMemsetAsync(d_out, 0, (size_t)out_size * sizeof(float), stream);

    k_efnorm<<<E, 64, 0, stream>>>(ef, D, efn, counts);  // also zeroes counts

    if (fullPath) {
        k_scores3<<<B / 16, 256, 0, stream>>>(x, ef, trust, stale, efn,
                                              kp, D, B, xbf, counts, lists, sel);
        int perExpF4 = (C * D) / 4;
        dim3 wgrid((perExpF4 + 1023) / 1024, E);
        k_prep_w<<<wgrid, 256, 0, stream>>>(W, counts, perExpF4, wbf, offs);
        dim3 grid((B + 127) / 128, C / 128, E);
        k_moe3<<<grid, 512, 0, stream>>>(xbf, wbf, b, lists, counts, offs, kp,
                                         B, C, D, usePart, part, out);
        if (usePart)
            k_combine<<<B / 4, 256, 0, stream>>>(part, sel, offs, kp, C, out);
    } else {
        k_scores_legacy<<<B / 32, 256, 0, stream>>>(x, ef, trust, stale, efn,
                                                    kp, D, B, counts, lists);
        dim3 grid((B + 127) / 128, C / 256, E);
        k_moe_f32<<<grid, 512, 0, stream>>>(x, W, b, lists, counts, kp,
                                            B, C, D, out);
    }
}